// Round 2
// baseline (253.376 us; speedup 1.0000x reference)
//
#include <hip/hip_runtime.h>
#include <hip/hip_bf16.h>

typedef __attribute__((ext_vector_type(8))) short short8;
typedef __attribute__((ext_vector_type(4))) short short4v;
typedef __attribute__((ext_vector_type(4))) float floatx4;

#define SEQ   2048
#define EMB   1024
#define HEAD  64
#define BATCH 8

__device__ __forceinline__ short f2bf(float f) {
    union { float f; unsigned u; } a; a.f = f;
    unsigned u = a.u;
    u = (u + 0x7FFFu + ((u >> 16) & 1u)) >> 16;   // round-to-nearest-even
    return (short)u;
}

// Wt layout: [3][HEAD][EMB] bf16, mat 0 = Wq, 1 = Wk, 2 = Wv (transposed from [EMB][HEAD] fp32)
__global__ void wtrans_kernel(const float* __restrict__ Wk,
                              const float* __restrict__ Wq,
                              const float* __restrict__ Wv,
                              short* __restrict__ Wt) {
    int mat   = blockIdx.x >> 6;     // 0..2
    int chunk = blockIdx.x & 63;     // covers 16 k-rows
    const float* src = (mat == 0) ? Wq : (mat == 1) ? Wk : Wv;
    short* dst = Wt + mat * (HEAD * EMB);
    #pragma unroll
    for (int i = 0; i < 4; ++i) {
        int idx = chunk * 1024 + i * 256 + threadIdx.x;  // idx = k*64 + n
        int kk = idx >> 6, n = idx & 63;
        dst[n * EMB + kk] = f2bf(src[idx]);
    }
}

// q,k: [B][S][HEAD] bf16 row-major.  vt: [B][HEAD][S] bf16 (transposed).
__global__ __launch_bounds__(256) void qkv_kernel(const float* __restrict__ x,
                                                  const short* __restrict__ Wt,
                                                  short* __restrict__ q,
                                                  short* __restrict__ k,
                                                  short* __restrict__ vt) {
    const int wave = threadIdx.x >> 6;
    const int lane = threadIdx.x & 63;
    const int l15  = lane & 15;
    const int quad = lane >> 4;
    const int row0 = blockIdx.x * 64 + wave * 16;

    floatx4 acc[3][4];
    #pragma unroll
    for (int m = 0; m < 3; ++m)
        #pragma unroll
        for (int nt = 0; nt < 4; ++nt)
            acc[m][nt] = (floatx4){0.f, 0.f, 0.f, 0.f};

    const float* xrow = x + (long)(row0 + l15) * EMB + quad * 8;

    for (int k0 = 0; k0 < EMB; k0 += 32) {
        floatx4 xa = *(const floatx4*)(xrow + k0);
        floatx4 xb = *(const floatx4*)(xrow + k0 + 4);
        short8 a;
        #pragma unroll
        for (int i = 0; i < 4; ++i) { a[i] = f2bf(xa[i]); a[4 + i] = f2bf(xb[i]); }
        #pragma unroll
        for (int m = 0; m < 3; ++m) {
            #pragma unroll
            for (int nt = 0; nt < 4; ++nt) {
                const short* bp = Wt + m * (HEAD * EMB) + (nt * 16 + l15) * EMB + quad * 8 + k0;
                short8 b = *(const short8*)bp;
                acc[m][nt] = __builtin_amdgcn_mfma_f32_16x16x32_bf16(a, b, acc[m][nt], 0, 0, 0);
            }
        }
    }

    const int bidx = row0 >> 11;                 // batch (SEQ = 2048)
    const int srow = (row0 & (SEQ - 1)) + quad * 4;
    #pragma unroll
    for (int nt = 0; nt < 4; ++nt) {
        const int col = nt * 16 + l15;
        #pragma unroll
        for (int r = 0; r < 4; ++r) {
            long grow = (long)(row0 + quad * 4 + r);
            q[grow * HEAD + col] = f2bf(acc[0][nt][r]);
            k[grow * HEAD + col] = f2bf(acc[1][nt][r]);
        }
        short4v vv;
        #pragma unroll
        for (int r = 0; r < 4; ++r) vv[r] = f2bf(acc[2][nt][r]);
        *(short4v*)(vt + ((long)bidx * HEAD + col) * SEQ + srow) = vv;
    }
}

// Flash attention, causal. 1 wave/block; wave handles qtile pair (p, 127-p):
// exactly 65 key-tiles (BK=32) per wave -> perfectly balanced grid.
__global__ __launch_bounds__(64) void attn_kernel(const short* __restrict__ q,
                                                  const short* __restrict__ k,
                                                  const short* __restrict__ vt,
                                                  float* __restrict__ out) {
    __shared__ short Plds[16][32];
    const int lane = threadIdx.x;
    const int l15  = lane & 15;
    const int quad = lane >> 4;
    const int b    = blockIdx.x >> 6;
    const int p    = blockIdx.x & 63;

    #pragma unroll 1
    for (int which = 0; which < 2; ++which) {
        const int t  = which ? (127 - p) : p;
        const int s0 = t * 16;

        const short* qb = q + ((long)b * SEQ + s0 + l15) * HEAD + quad * 8;
        short8 qf0 = *(const short8*)(qb);
        short8 qf1 = *(const short8*)(qb + 32);

        floatx4 o[4];
        #pragma unroll
        for (int nt = 0; nt < 4; ++nt) o[nt] = (floatx4){0.f, 0.f, 0.f, 0.f};
        float m_i[4], l_i[4];
        #pragma unroll
        for (int r = 0; r < 4; ++r) { m_i[r] = -1e30f; l_i[r] = 0.f; }

        const int nkeys = s0 + 16;
        for (int j0 = 0; j0 < nkeys; j0 += 32) {
            // ---- S = Q K^T (2 key n-tiles x 2 d k-steps) ----
            floatx4 sa[2];
            sa[0] = (floatx4){0.f, 0.f, 0.f, 0.f};
            sa[1] = (floatx4){0.f, 0.f, 0.f, 0.f};
            #pragma unroll
            for (int nt = 0; nt < 2; ++nt) {
                const short* kb = k + ((long)b * SEQ + j0 + nt * 16 + l15) * HEAD + quad * 8;
                short8 kf0 = *(const short8*)(kb);
                short8 kf1 = *(const short8*)(kb + 32);
                sa[nt] = __builtin_amdgcn_mfma_f32_16x16x32_bf16(qf0, kf0, sa[nt], 0, 0, 0);
                sa[nt] = __builtin_amdgcn_mfma_f32_16x16x32_bf16(qf1, kf1, sa[nt], 0, 0, 0);
            }

            // ---- scale + causal mask + row max ----
            float mt[4], ps[4];
            #pragma unroll
            for (int r = 0; r < 4; ++r) {
                const int sq = s0 + quad * 4 + r;
                #pragma unroll
                for (int nt = 0; nt < 2; ++nt) {
                    const int sk = j0 + nt * 16 + l15;
                    float v = sa[nt][r] * 0.125f;
                    sa[nt][r] = (sk > sq) ? -1e30f : v;
                }
                mt[r] = fmaxf(sa[0][r], sa[1][r]);
            }
            #pragma unroll
            for (int msk = 1; msk <= 8; msk <<= 1) {
                #pragma unroll
                for (int r = 0; r < 4; ++r)
                    mt[r] = fmaxf(mt[r], __shfl_xor(mt[r], msk, 64));
            }

            // ---- online softmax update ----
            #pragma unroll
            for (int r = 0; r < 4; ++r) {
                float mnew  = fmaxf(m_i[r], mt[r]);
                float alpha = __expf(m_i[r] - mnew);
                m_i[r] = mnew;
                l_i[r] *= alpha;
                #pragma unroll
                for (int nt = 0; nt < 4; ++nt) o[nt][r] *= alpha;
                float p0 = __expf(sa[0][r] - mnew);
                float p1 = __expf(sa[1][r] - mnew);
                sa[0][r] = p0; sa[1][r] = p1;
                ps[r] = p0 + p1;
            }
            #pragma unroll
            for (int msk = 1; msk <= 8; msk <<= 1) {
                #pragma unroll
                for (int r = 0; r < 4; ++r)
                    ps[r] += __shfl_xor(ps[r], msk, 64);
            }
            #pragma unroll
            for (int r = 0; r < 4; ++r) l_i[r] += ps[r];

            // ---- P: C-layout -> A-layout via LDS ----
            #pragma unroll
            for (int nt = 0; nt < 2; ++nt)
                #pragma unroll
                for (int r = 0; r < 4; ++r)
                    Plds[quad * 4 + r][nt * 16 + l15] = f2bf(sa[nt][r]);
            __syncthreads();
            short8 pf = *(const short8*)(&Plds[l15][quad * 8]);

            // ---- O += P V (4 d n-tiles, K=32 keys) ----
            #pragma unroll
            for (int nt = 0; nt < 4; ++nt) {
                const short* vb = vt + ((long)b * HEAD + nt * 16 + l15) * SEQ + j0 + quad * 8;
                short8 vf = *(const short8*)(vb);
                o[nt] = __builtin_amdgcn_mfma_f32_16x16x32_bf16(pf, vf, o[nt], 0, 0, 0);
            }
            __syncthreads();
        }

        // ---- epilogue: O / l, fp32 out ----
        #pragma unroll
        for (int nt = 0; nt < 4; ++nt) {
            const int col = nt * 16 + l15;
            #pragma unroll
            for (int r = 0; r < 4; ++r) {
                const int row = s0 + quad * 4 + r;
                out[((long)b * SEQ + row) * HEAD + col] = o[nt][r] / l_i[r];
            }
        }
    }
}

extern "C" void kernel_launch(void* const* d_in, const int* in_sizes, int n_in,
                              void* d_out, int out_size, void* d_ws, size_t ws_size,
                              hipStream_t stream) {
    const float* x  = (const float*)d_in[0];
    const float* Wk = (const float*)d_in[1];
    const float* Wq = (const float*)d_in[2];
    const float* Wv = (const float*)d_in[3];
    float* out = (float*)d_out;

    short* Wt = (short*)d_ws;                          // 3*64*1024 bf16 = 384 KiB
    short* q  = Wt + 3 * HEAD * EMB;                   // 2 MiB each
    short* k  = q + (long)BATCH * SEQ * HEAD;
    short* vt = k + (long)BATCH * SEQ * HEAD;

    hipLaunchKernelGGL(wtrans_kernel, dim3(192), dim3(256), 0, stream, Wk, Wq, Wv, Wt);
    hipLaunchKernelGGL(qkv_kernel, dim3(BATCH * SEQ / 64), dim3(256), 0, stream, x, Wt, q, k, vt);
    hipLaunchKernelGGL(attn_kernel, dim3(BATCH * 64), dim3(64), 0, stream, q, k, vt, out);
}

// Round 3
// 160.641 us; speedup vs baseline: 1.5773x; 1.5773x over previous
//
#include <hip/hip_runtime.h>
#include <hip/hip_bf16.h>

typedef __attribute__((ext_vector_type(8))) short short8;
typedef __attribute__((ext_vector_type(4))) short short4v;
typedef __attribute__((ext_vector_type(4))) float floatx4;

#define SEQ   2048
#define EMB   1024
#define HEAD  64
#define BATCH 8

__device__ __forceinline__ short f2bf(float f) {
    union { float f; unsigned u; } a; a.f = f;
    unsigned u = a.u;
    u = (u + 0x7FFFu + ((u >> 16) & 1u)) >> 16;   // round-to-nearest-even
    return (short)u;
}

// Wf: MFMA-fragment-ordered weights, bf16.
// fragid f = (mat*4 + nt)*32 + kchunk  (kchunk = k0/32), mat 0=Wq 1=Wk 2=Wv.
// Wf[f*512 + lane*8 + j] = W[k = kchunk*32 + (lane>>4)*8 + j][h = nt*16 + (lane&15)]
__global__ void wtrans_kernel(const float* __restrict__ Wk,
                              const float* __restrict__ Wq,
                              const float* __restrict__ Wv,
                              short* __restrict__ Wf) {
    int gid  = blockIdx.x * 256 + threadIdx.x;   // 24576 total
    int lane = gid & 63;
    int fid  = gid >> 6;                          // 0..383
    int chunk = fid & 31;
    int mnt  = fid >> 5;                          // mat*4+nt
    int mat  = mnt >> 2, nt = mnt & 3;
    const float* src = (mat == 0) ? Wq : (mat == 1) ? Wk : Wv;
    int n = lane & 15, quad = lane >> 4;
    int h = nt * 16 + n;
    short8 o8;
    #pragma unroll
    for (int j = 0; j < 8; ++j) {
        int kk = chunk * 32 + quad * 8 + j;
        o8[j] = f2bf(src[kk * 64 + h]);
    }
    *(short8*)(Wf + (long)gid * 8) = o8;
}

// Block: 16 rows x 192 cols, 4 waves split K into quarters; LDS reduce.
__global__ __launch_bounds__(256) void qkv_kernel(const float* __restrict__ x,
                                                  const short* __restrict__ Wf,
                                                  short* __restrict__ q,
                                                  short* __restrict__ k,
                                                  short* __restrict__ vt) {
    __shared__ float red[3][64][48];   // waves 1..3 partials
    const int wv   = threadIdx.x >> 6;
    const int lane = threadIdx.x & 63;
    const int l15  = lane & 15;
    const int quad = lane >> 4;
    const int row0 = blockIdx.x * 16;

    floatx4 acc[3][4];
    #pragma unroll
    for (int m = 0; m < 3; ++m)
        #pragma unroll
        for (int nt = 0; nt < 4; ++nt)
            acc[m][nt] = (floatx4){0.f, 0.f, 0.f, 0.f};

    const float* xrow = x + (long)(row0 + l15) * EMB + quad * 8;
    const int kbase = wv * 256;

    #pragma unroll 2
    for (int kk = 0; kk < 256; kk += 32) {
        const int k0 = kbase + kk;
        floatx4 xa = *(const floatx4*)(xrow + k0);
        floatx4 xb = *(const floatx4*)(xrow + k0 + 4);
        short8 a;
        #pragma unroll
        for (int i = 0; i < 4; ++i) { a[i] = f2bf(xa[i]); a[4 + i] = f2bf(xb[i]); }
        const int cidx = k0 >> 5;
        #pragma unroll
        for (int m = 0; m < 3; ++m) {
            #pragma unroll
            for (int nt = 0; nt < 4; ++nt) {
                short8 b = *(const short8*)(Wf + ((long)((m * 4 + nt) * 32 + cidx) * 64 + lane) * 8);
                acc[m][nt] = __builtin_amdgcn_mfma_f32_16x16x32_bf16(a, b, acc[m][nt], 0, 0, 0);
            }
        }
    }

    if (wv > 0) {
        #pragma unroll
        for (int m = 0; m < 3; ++m)
            #pragma unroll
            for (int nt = 0; nt < 4; ++nt)
                #pragma unroll
                for (int r = 0; r < 4; ++r)
                    red[wv - 1][lane][(m * 4 + nt) * 4 + r] = acc[m][nt][r];
    }
    __syncthreads();
    if (wv == 0) {
        #pragma unroll
        for (int w = 0; w < 3; ++w)
            #pragma unroll
            for (int m = 0; m < 3; ++m)
                #pragma unroll
                for (int nt = 0; nt < 4; ++nt)
                    #pragma unroll
                    for (int r = 0; r < 4; ++r)
                        acc[m][nt][r] += red[w][lane][(m * 4 + nt) * 4 + r];

        const int bidx = row0 >> 11;
        const int srow = (row0 & (SEQ - 1)) + quad * 4;
        #pragma unroll
        for (int nt = 0; nt < 4; ++nt) {
            const int col = nt * 16 + l15;
            #pragma unroll
            for (int r = 0; r < 4; ++r) {
                long grow = (long)(row0 + quad * 4 + r);
                q[grow * HEAD + col] = f2bf(acc[0][nt][r]);
                k[grow * HEAD + col] = f2bf(acc[1][nt][r]);
            }
            short4v vv;
            #pragma unroll
            for (int r = 0; r < 4; ++r) vv[r] = f2bf(acc[2][nt][r]);
            *(short4v*)(vt + ((long)bidx * HEAD + col) * SEQ + srow) = vv;
        }
    }
}

// Flash attention, causal. Block = one q-tile (16 rows), 4 waves split the
// key range into contiguous 32-key chunk ranges; flash-merge via LDS.
// Grid ordered large-t first for tail balance.
__global__ __launch_bounds__(256) void attn_kernel(const short* __restrict__ q,
                                                   const short* __restrict__ k,
                                                   const short* __restrict__ vt,
                                                   float* __restrict__ out) {
    __shared__ short Plds[4][16][32];
    __shared__ float oA[3][16][64];
    __shared__ float mA[3][16];
    __shared__ float lA[3][16];

    const int wv   = threadIdx.x >> 6;
    const int lane = threadIdx.x & 63;
    const int l15  = lane & 15;
    const int quad = lane >> 4;
    const int b    = blockIdx.x & 7;
    const int t    = 127 - (blockIdx.x >> 3);
    const int s0   = t * 16;

    const int nch  = (t + 2) >> 1;          // ceil(16(t+1)/32)
    const int c0   = (nch * wv) >> 2;
    const int c1   = (nch * (wv + 1)) >> 2;
    const int cmax = (nch + 3) >> 2;        // uniform loop count per block

    const short* qb = q + ((long)b * SEQ + s0 + l15) * HEAD + quad * 8;
    short8 qf0 = *(const short8*)(qb);
    short8 qf1 = *(const short8*)(qb + 32);

    floatx4 o[4];
    #pragma unroll
    for (int nt = 0; nt < 4; ++nt) o[nt] = (floatx4){0.f, 0.f, 0.f, 0.f};
    float m_i[4], l_i[4];
    #pragma unroll
    for (int r = 0; r < 4; ++r) { m_i[r] = -1e30f; l_i[r] = 0.f; }

    for (int i = 0; i < cmax; ++i) {
        const int c = c0 + i;
        const bool active = (c < c1);
        const int j0 = c * 32;              // proven <= 32*(nch-1), in-bounds

        // ---- S = Q K^T ----
        floatx4 sa[2];
        sa[0] = (floatx4){0.f, 0.f, 0.f, 0.f};
        sa[1] = (floatx4){0.f, 0.f, 0.f, 0.f};
        #pragma unroll
        for (int nt = 0; nt < 2; ++nt) {
            const short* kb = k + ((long)b * SEQ + j0 + nt * 16 + l15) * HEAD + quad * 8;
            short8 kf0 = *(const short8*)(kb);
            short8 kf1 = *(const short8*)(kb + 32);
            sa[nt] = __builtin_amdgcn_mfma_f32_16x16x32_bf16(qf0, kf0, sa[nt], 0, 0, 0);
            sa[nt] = __builtin_amdgcn_mfma_f32_16x16x32_bf16(qf1, kf1, sa[nt], 0, 0, 0);
        }

        // ---- scale + mask (also masks inactive dummy iterations) ----
        float mt[4];
        #pragma unroll
        for (int r = 0; r < 4; ++r) {
            const int sq = s0 + quad * 4 + r;
            #pragma unroll
            for (int nt = 0; nt < 2; ++nt) {
                const int sk = j0 + nt * 16 + l15;
                float v = sa[nt][r] * 0.125f;
                sa[nt][r] = (!active || sk > sq) ? -1e30f : v;
            }
            mt[r] = fmaxf(sa[0][r], sa[1][r]);
        }
        #pragma unroll
        for (int msk = 1; msk <= 8; msk <<= 1) {
            #pragma unroll
            for (int r = 0; r < 4; ++r)
                mt[r] = fmaxf(mt[r], __shfl_xor(mt[r], msk, 64));
        }

        // ---- online softmax update (guard: masked/empty entries give p=0) ----
        float ps[4];
        #pragma unroll
        for (int r = 0; r < 4; ++r) {
            float mnew  = fmaxf(m_i[r], mt[r]);
            float alpha = __expf(m_i[r] - mnew);
            m_i[r] = mnew;
            l_i[r] *= alpha;
            #pragma unroll
            for (int nt = 0; nt < 4; ++nt) o[nt][r] *= alpha;
            float p0 = (sa[0][r] < -1e29f) ? 0.f : __expf(sa[0][r] - mnew);
            float p1 = (sa[1][r] < -1e29f) ? 0.f : __expf(sa[1][r] - mnew);
            sa[0][r] = p0; sa[1][r] = p1;
            ps[r] = p0 + p1;
        }
        #pragma unroll
        for (int msk = 1; msk <= 8; msk <<= 1) {
            #pragma unroll
            for (int r = 0; r < 4; ++r)
                ps[r] += __shfl_xor(ps[r], msk, 64);
        }
        #pragma unroll
        for (int r = 0; r < 4; ++r) l_i[r] += ps[r];

        // ---- P: C-layout -> A-layout via per-wave LDS buffer ----
        #pragma unroll
        for (int nt = 0; nt < 2; ++nt)
            #pragma unroll
            for (int r = 0; r < 4; ++r)
                Plds[wv][quad * 4 + r][nt * 16 + l15] = f2bf(sa[nt][r]);
        __syncthreads();   // uniform count across block; fences write->read
        short8 pf = *(const short8*)(&Plds[wv][l15][quad * 8]);

        // ---- O += P V ----
        #pragma unroll
        for (int nt = 0; nt < 4; ++nt) {
            const short* vb = vt + ((long)b * HEAD + nt * 16 + l15) * SEQ + j0 + quad * 8;
            short8 vf = *(const short8*)(vb);
            o[nt] = __builtin_amdgcn_mfma_f32_16x16x32_bf16(pf, vf, o[nt], 0, 0, 0);
        }
    }

    // ---- flash merge across the 4 waves ----
    if (wv > 0) {
        #pragma unroll
        for (int nt = 0; nt < 4; ++nt)
            #pragma unroll
            for (int r = 0; r < 4; ++r)
                oA[wv - 1][quad * 4 + r][nt * 16 + l15] = o[nt][r];
        if (l15 == 0) {
            #pragma unroll
            for (int r = 0; r < 4; ++r) {
                mA[wv - 1][quad * 4 + r] = m_i[r];
                lA[wv - 1][quad * 4 + r] = l_i[r];
            }
        }
    }
    __syncthreads();
    if (wv == 0) {
        #pragma unroll
        for (int r = 0; r < 4; ++r) {
            const int row = quad * 4 + r;
            float M = m_i[r];
            #pragma unroll
            for (int w = 0; w < 3; ++w) M = fmaxf(M, mA[w][row]);
            float sc = __expf(m_i[r] - M);
            float lsum = l_i[r] * sc;
            float ov[4];
            #pragma unroll
            for (int nt = 0; nt < 4; ++nt) ov[nt] = o[nt][r] * sc;
            #pragma unroll
            for (int w = 0; w < 3; ++w) {
                float sw = __expf(mA[w][row] - M);
                lsum += lA[w][row] * sw;
                #pragma unroll
                for (int nt = 0; nt < 4; ++nt)
                    ov[nt] += sw * oA[w][row][nt * 16 + l15];
            }
            const float inv = 1.f / lsum;
            #pragma unroll
            for (int nt = 0; nt < 4; ++nt)
                out[((long)b * SEQ + s0 + row) * HEAD + nt * 16 + l15] = ov[nt] * inv;
        }
    }
}

extern "C" void kernel_launch(void* const* d_in, const int* in_sizes, int n_in,
                              void* d_out, int out_size, void* d_ws, size_t ws_size,
                              hipStream_t stream) {
    const float* x  = (const float*)d_in[0];
    const float* Wk = (const float*)d_in[1];
    const float* Wq = (const float*)d_in[2];
    const float* Wv = (const float*)d_in[3];
    float* out = (float*)d_out;

    short* Wf = (short*)d_ws;                          // 384 KiB
    short* q  = Wf + 3 * HEAD * EMB;                   // 2 MiB each
    short* k  = q + (long)BATCH * SEQ * HEAD;
    short* vt = k + (long)BATCH * SEQ * HEAD;

    hipLaunchKernelGGL(wtrans_kernel, dim3(96), dim3(256), 0, stream, Wk, Wq, Wv, Wf);
    hipLaunchKernelGGL(qkv_kernel, dim3(BATCH * SEQ / 16), dim3(256), 0, stream, x, Wf, q, k, vt);
    hipLaunchKernelGGL(attn_kernel, dim3(BATCH * 128), dim3(256), 0, stream, q, k, vt, out);
}